// Round 1
// baseline (68.027 us; speedup 1.0000x reference)
//
#include <hip/hip_runtime.h>

// Problem constants (match reference).
#define N_CAT    1024
#define B_DIM    16
#define L_DIM    4096
#define MASK_IDX 1023
#define EPS      1e-8f

// ---------------------------------------------------------------------------
// Kernel 1: per-row logsumexp of W, plus diagonal table D[r] = W[r,r] - lse[r].
// One 256-thread block per row; each thread holds 4 contiguous floats in regs.
// ---------------------------------------------------------------------------
__global__ __launch_bounds__(256) void lse_kernel(const float* __restrict__ W,
                                                  float* __restrict__ lse,
                                                  float* __restrict__ D) {
    const int r   = blockIdx.x;
    const int tid = threadIdx.x;

    const float4 v = *reinterpret_cast<const float4*>(W + (size_t)r * N_CAT + tid * 4);

    // --- block max ---
    float m = fmaxf(fmaxf(v.x, v.y), fmaxf(v.z, v.w));
    #pragma unroll
    for (int off = 32; off > 0; off >>= 1)
        m = fmaxf(m, __shfl_down(m, off, 64));

    __shared__ float smax[4];
    __shared__ float ssum[4];
    const int wave = tid >> 6, lane = tid & 63;
    if (lane == 0) smax[wave] = m;
    __syncthreads();
    const float bm = fmaxf(fmaxf(smax[0], smax[1]), fmaxf(smax[2], smax[3]));

    // --- block sum of exp ---
    float s = expf(v.x - bm) + expf(v.y - bm) + expf(v.z - bm) + expf(v.w - bm);
    #pragma unroll
    for (int off = 32; off > 0; off >>= 1)
        s += __shfl_down(s, off, 64);
    if (lane == 0) ssum[wave] = s;
    __syncthreads();

    if (tid == 0) {
        const float l = bm + logf(ssum[0] + ssum[1] + ssum[2] + ssum[3]);
        lse[r] = l;
        D[r]   = W[(size_t)r * N_CAT + r] - l;   // diagonal term, pre-subtracted
    }
}

// ---------------------------------------------------------------------------
// Kernel 2: per-position loss terms + reduction.
// 64 blocks x 256 threads; 4 blocks per batch row b, 4 positions per thread.
// term = keep ? D[x] : (W[1023, x] - lse[1023])   -- only 4KB tables touched.
// ---------------------------------------------------------------------------
__global__ __launch_bounds__(256) void loss_kernel(const int*   __restrict__ x,
                                                   const float* __restrict__ u,
                                                   const float* __restrict__ noise,
                                                   const float* __restrict__ W,
                                                   const float* __restrict__ lse,
                                                   const float* __restrict__ D,
                                                   float* __restrict__ out) {
    const int b   = blockIdx.x >> 2;        // batch row
    const int seg = blockIdx.x & 3;         // quarter of the row
    const int tid = threadIdx.x;

    const float t     = fmodf(u[0] + (float)b * (1.0f / (float)B_DIM), 1.0f);
    const float alpha = 1.0f - t;
    const float wgt   = -1.0f / fmaxf(t, EPS);
    const float lseM  = lse[MASK_IDX];
    const float* WmaskRow = W + (size_t)MASK_IDX * N_CAT;

    const int base = b * L_DIM + seg * 1024 + tid * 4;
    const int4   xv = *reinterpret_cast<const int4*>(x + base);
    const float4 nv = *reinterpret_cast<const float4*>(noise + base);

    const int   xs[4] = {xv.x, xv.y, xv.z, xv.w};
    const float ns[4] = {nv.x, nv.y, nv.z, nv.w};

    float sum = 0.0f;
    #pragma unroll
    for (int i = 0; i < 4; ++i) {
        const int xi = xs[i];
        const float term = (ns[i] < alpha) ? D[xi] : (WmaskRow[xi] - lseM);
        sum += term;
    }

    // --- block reduction (4 waves) ---
    #pragma unroll
    for (int off = 32; off > 0; off >>= 1)
        sum += __shfl_down(sum, off, 64);

    __shared__ float swave[4];
    const int wave = tid >> 6, lane = tid & 63;
    if (lane == 0) swave[wave] = sum;
    __syncthreads();

    if (wave == 0) {
        float v = (lane < 4) ? swave[lane] : 0.0f;
        #pragma unroll
        for (int off = 2; off > 0; off >>= 1)
            v += __shfl_down(v, off, 64);
        if (lane == 0)
            atomicAdd(out, wgt * v * (1.0f / (float)B_DIM));
    }
}

// ---------------------------------------------------------------------------
extern "C" void kernel_launch(void* const* d_in, const int* in_sizes, int n_in,
                              void* d_out, int out_size, void* d_ws, size_t ws_size,
                              hipStream_t stream) {
    const int*   x     = (const int*)  d_in[0];   // [B, L] int32
    const float* u     = (const float*)d_in[1];   // [1]
    const float* noise = (const float*)d_in[2];   // [B, L]
    const float* W     = (const float*)d_in[3];   // [N, N]
    float*       out   = (float*)d_out;           // scalar

    float* lse = (float*)d_ws;                    // [1024]
    float* D   = (float*)d_ws + N_CAT;            // [1024]

    // d_out is poisoned 0xAA before every launch -> zero it (capturable op).
    hipMemsetAsync(out, 0, sizeof(float), stream);

    lse_kernel<<<N_CAT, 256, 0, stream>>>(W, lse, D);
    loss_kernel<<<B_DIM * 4, 256, 0, stream>>>(x, u, noise, W, lse, D, out);
}

// Round 2
// 67.684 us; speedup vs baseline: 1.0051x; 1.0051x over previous
//
#include <hip/hip_runtime.h>

// Problem constants (match reference).
#define N_CAT    1024
#define B_DIM    16
#define L_DIM    4096
#define MASK_IDX 1023
#define EPS      1e-8f

// ---------------------------------------------------------------------------
// Kernel 1: per-row logsumexp of W, diagonal table D[r] = W[r,r] - lse[r].
// One 256-thread block per row; each thread holds 4 contiguous floats in regs.
// Block 0 also zeroes d_out (runs before loss_kernel in stream order), which
// removes the separate memset graph node.
// ---------------------------------------------------------------------------
__global__ __launch_bounds__(256) void lse_kernel(const float* __restrict__ W,
                                                  float* __restrict__ lse,
                                                  float* __restrict__ D,
                                                  float* __restrict__ out) {
    const int r   = blockIdx.x;
    const int tid = threadIdx.x;

    if (r == 0 && tid == 0) out[0] = 0.0f;   // replaces hipMemsetAsync node

    const float4 v = *reinterpret_cast<const float4*>(W + (size_t)r * N_CAT + tid * 4);

    // --- block max ---
    float m = fmaxf(fmaxf(v.x, v.y), fmaxf(v.z, v.w));
    #pragma unroll
    for (int off = 32; off > 0; off >>= 1)
        m = fmaxf(m, __shfl_down(m, off, 64));

    __shared__ float smax[4];
    __shared__ float ssum[4];
    const int wave = tid >> 6, lane = tid & 63;
    if (lane == 0) smax[wave] = m;
    __syncthreads();
    const float bm = fmaxf(fmaxf(smax[0], smax[1]), fmaxf(smax[2], smax[3]));

    // --- block sum of exp ---
    float s = expf(v.x - bm) + expf(v.y - bm) + expf(v.z - bm) + expf(v.w - bm);
    #pragma unroll
    for (int off = 32; off > 0; off >>= 1)
        s += __shfl_down(s, off, 64);
    if (lane == 0) ssum[wave] = s;
    __syncthreads();

    if (tid == 0) {
        const float l = bm + logf(ssum[0] + ssum[1] + ssum[2] + ssum[3]);
        lse[r] = l;
        D[r]   = W[(size_t)r * N_CAT + r] - l;   // diagonal term, pre-subtracted
    }
}

// ---------------------------------------------------------------------------
// Kernel 2: per-position loss terms + reduction.
// 256 blocks x 256 threads, exactly 1 position per thread (B*L = 65536).
// Max TLP, 1-deep gather chain. Tables D (4KB) and W's mask row (4KB) are
// L1/L2-resident; streaming reads are x + noise = 512 KB total.
// ---------------------------------------------------------------------------
__global__ __launch_bounds__(256) void loss_kernel(const int*   __restrict__ x,
                                                   const float* __restrict__ u,
                                                   const float* __restrict__ noise,
                                                   const float* __restrict__ W,
                                                   const float* __restrict__ lse,
                                                   const float* __restrict__ D,
                                                   float* __restrict__ out) {
    const int gid = blockIdx.x * 256 + threadIdx.x;   // position index in [0, B*L)
    const int b   = gid >> 12;                        // gid / L_DIM
    const int tid = threadIdx.x;

    const float t     = fmodf(u[0] + (float)b * (1.0f / (float)B_DIM), 1.0f);
    const float alpha = 1.0f - t;
    const float wgt   = -1.0f / fmaxf(t, EPS);
    const float lseM  = lse[MASK_IDX];
    const float* __restrict__ WmaskRow = W + (size_t)MASK_IDX * N_CAT;

    const int   xi = x[gid];
    const float ni = noise[gid];

    // term already scaled by weight[b]/B (weight is block... per-thread uniform in b
    // only within a block? 256 | 4096, so each block spans one b. Scale per-thread.)
    const float term = (ni < alpha) ? D[xi] : (WmaskRow[xi] - lseM);
    float sum = wgt * term * (1.0f / (float)B_DIM);

    // --- block reduction (4 waves) ---
    #pragma unroll
    for (int off = 32; off > 0; off >>= 1)
        sum += __shfl_down(sum, off, 64);

    __shared__ float swave[4];
    const int wave = tid >> 6, lane = tid & 63;
    if (lane == 0) swave[wave] = sum;
    __syncthreads();

    if (wave == 0) {
        float v = (lane < 4) ? swave[lane] : 0.0f;
        #pragma unroll
        for (int off = 2; off > 0; off >>= 1)
            v += __shfl_down(v, off, 64);
        if (lane == 0)
            atomicAdd(out, v);
    }
}

// ---------------------------------------------------------------------------
extern "C" void kernel_launch(void* const* d_in, const int* in_sizes, int n_in,
                              void* d_out, int out_size, void* d_ws, size_t ws_size,
                              hipStream_t stream) {
    const int*   x     = (const int*)  d_in[0];   // [B, L] int32
    const float* u     = (const float*)d_in[1];   // [1]
    const float* noise = (const float*)d_in[2];   // [B, L]
    const float* W     = (const float*)d_in[3];   // [N, N]
    float*       out   = (float*)d_out;           // scalar

    float* lse = (float*)d_ws;                    // [1024]
    float* D   = (float*)d_ws + N_CAT;            // [1024]

    lse_kernel<<<N_CAT, 256, 0, stream>>>(W, lse, D, out);
    loss_kernel<<<(B_DIM * L_DIM) / 256, 256, 0, stream>>>(x, u, noise, W, lse, D, out);
}